// Round 5
// baseline (110.904 us; speedup 1.0000x reference)
//
#include <hip/hip_runtime.h>

#define BB   128
#define TT   512
#define FF   40
#define WW   10
#define NS   503            // window starts (stride 1): T-W+1
#define NP   780            // F*(F-1)/2
#define SC   64             // steps per block (uniform; last chunk overlaps)
#define NCHUNK 8
#define ROWS (SC + WW - 1)  // 73 staged rows
#define NSTRIP 210          // 1x4 j-strips covering the upper triangle
#define EPSC 1e-5f

// One block per (b, 64-step s-chunk).
//  phase 0: stage xs[73][40] (contiguous slab, float4)
//  phase 1: stats st[t][f]=(istd, m*istd) for all 64 steps, float4-vectorized
//  phase 2: barrier-free rolling loop. Thread owns strip (i, j0..j0+3), j0%4==0:
//           per step 1 b32 + 2 b128 + 1 b64 LDS reads cover 4 pairs.
//           Product history ph[4][10] in registers, statically indexed.
__global__ __launch_bounds__(256, 4) void ts_corr_strip(const float* __restrict__ in,
                                                        float* __restrict__ out) {
    const int blk = blockIdx.x;
    const int b   = blk / NCHUNK;
    const int c   = blk - b * NCHUNK;
    const int s0  = (c == NCHUNK - 1) ? (NS - SC) : c * SC;   // overlap tail, identical writes
    const int tid = threadIdx.x;

    __shared__ float  xs[ROWS][FF];     // 11680 B
    __shared__ float2 st[SC][FF];       // 20480 B  (istd, m*istd)

    // ---- phase 0: stage slab ----
    const float4* src4 = (const float4*)(in + ((size_t)b * TT + s0) * FF);
    float4* xs4 = (float4*)&xs[0][0];
    #pragma unroll
    for (int k = 0; k < 3; ++k) {
        const int idx = tid + k * 256;
        if (idx < ROWS * FF / 4) xs4[idx] = src4[idx];
    }
    __syncthreads();

    // ---- phase 1: stats, 640 feature-quads (t, f0=4q) ----
    #pragma unroll
    for (int k = 0; k < 3; ++k) {
        const int qd = tid + k * 256;
        if (qd < SC * FF / 4) {
            const int t  = qd / 10;
            const int f0 = (qd - t * 10) * 4;
            float sx0=0,sx1=0,sx2=0,sx3=0, sq0=0,sq1=0,sq2=0,sq3=0;
            #pragma unroll
            for (int w = 0; w < WW; ++w) {
                const float4 x = *(const float4*)&xs[t + w][f0];
                sx0 += x.x; sx1 += x.y; sx2 += x.z; sx3 += x.w;
                sq0 += x.x*x.x; sq1 += x.y*x.y; sq2 += x.z*x.z; sq3 += x.w*x.w;
            }
            const float m0 = sx0*0.1f, m1 = sx1*0.1f, m2 = sx2*0.1f, m3 = sx3*0.1f;
            const float u0 = 1.f/(sqrtf(fmaxf(sq0*0.1f - m0*m0, 0.f)) + EPSC);
            const float u1 = 1.f/(sqrtf(fmaxf(sq1*0.1f - m1*m1, 0.f)) + EPSC);
            const float u2 = 1.f/(sqrtf(fmaxf(sq2*0.1f - m2*m2, 0.f)) + EPSC);
            const float u3 = 1.f/(sqrtf(fmaxf(sq3*0.1f - m3*m3, 0.f)) + EPSC);
            *(float4*)&st[t][f0]     = make_float4(u0, m0*u0, u1, m1*u1);
            *(float4*)&st[t][f0 + 2] = make_float4(u2, m2*u2, u3, m3*u3);
        }
    }

    // ---- strip setup: tid -> (row i, j0), j0 = 4*ceil-block, 210 strips ----
    int row = 0, j0 = 0;
    const bool sact = (tid < NSTRIP);
    {
        int rem = sact ? tid : 0;
        for (int r = 0; r < FF; ++r) {
            const int cnt = 10 - ((r + 1) >> 2);
            if (rem < cnt) { row = r; j0 = (((r + 1) >> 2) + rem) << 2; break; }
            rem -= cnt;
        }
    }
    bool val[4];
    #pragma unroll
    for (int q = 0; q < 4; ++q) val[q] = sact && (j0 + q > row);
    const int rowoff = row * (79 - row) / 2 - row - 1;   // p = rowoff + j

    // ---- initial window products (xs ready since phase-0 barrier) ----
    float sxy[4] = {0.f, 0.f, 0.f, 0.f};
    float ph[4][WW];
    #pragma unroll
    for (int w = 0; w < WW; ++w) {
        const float  xi = xs[w][row];
        const float4 xj = *(const float4*)&xs[w][j0];
        const float p0 = xi*xj.x, p1 = xi*xj.y, p2 = xi*xj.z, p3 = xi*xj.w;
        ph[0][w] = p0; sxy[0] += p0;
        ph[1][w] = p1; sxy[1] += p1;
        ph[2][w] = p2; sxy[2] += p2;
        ph[3][w] = p3; sxy[3] += p3;
    }
    __syncthreads();   // st ready; no barriers after this

    if (!sact) return;

    // ---- phase 2: 64 steps, barrier-free ----
    float* dst0 = out + (size_t)(b * NS + s0) * NP + rowoff;
    for (int t0 = 0; t0 < SC; t0 += WW) {
        #pragma unroll
        for (int u = 0; u < WW; ++u) {
            const int t = t0 + u;
            if (t0 == 60 && u >= 4) break;        // SC=64 tail of last group
            const float2 sti = st[t][row];
            const float4 a0  = *(const float4*)&st[t][j0];
            const float4 a1  = *(const float4*)&st[t][j0 + 2];
            const float  sui = sti.x * 0.1f;
            float* dst = dst0 + (size_t)t * NP;
            if (val[0]) dst[j0]     = sxy[0] * sui * a0.x - sti.y * a0.y;
            if (val[1]) dst[j0 + 1] = sxy[1] * sui * a0.z - sti.y * a0.w;
            if (val[2]) dst[j0 + 2] = sxy[2] * sui * a1.x - sti.y * a1.y;
            if (val[3]) dst[j0 + 3] = sxy[3] * sui * a1.z - sti.y * a1.w;
            if (t + 1 < SC) {
                const float  xi = xs[t + WW][row];
                const float4 xj = *(const float4*)&xs[t + WW][j0];
                float pn;
                pn = xi*xj.x; sxy[0] += pn - ph[0][u]; ph[0][u] = pn;
                pn = xi*xj.y; sxy[1] += pn - ph[1][u]; ph[1][u] = pn;
                pn = xi*xj.z; sxy[2] += pn - ph[2][u]; ph[2][u] = pn;
                pn = xi*xj.w; sxy[3] += pn - ph[3][u]; ph[3][u] = pn;
            }
        }
    }
}

extern "C" void kernel_launch(void* const* d_in, const int* in_sizes, int n_in,
                              void* d_out, int out_size, void* d_ws, size_t ws_size,
                              hipStream_t stream) {
    const float* in = (const float*)d_in[0];
    float* out = (float*)d_out;
    ts_corr_strip<<<BB * NCHUNK, 256, 0, stream>>>(in, out);
}

// Round 6
// 47.339 us; speedup vs baseline: 2.3427x; 2.3427x over previous
//
#include <hip/hip_runtime.h>

#define BB   128
#define TT   512
#define FF   40
#define WW   10
#define NS   503            // window starts (stride 1): T-W+1
#define NP   780            // F*(F-1)/2
#define SC   64             // steps per block (uniform; last chunk overlaps)
#define NCHUNK 8
#define ROWS (SC + WW - 1)  // 73 staged rows
#define EPSC 1e-5f
#define C01  0.31622776601683794f   // sqrt(0.1)

// One block per (b, 64-step s-chunk). Round-4 structure (coalesced p=tid+k*256
// stores) + 2-step-fused inner body so paired LDS reads (offset delta = 40
// dwords / 40 qwords) merge into ds_read2_b32 / ds_read2_b64, halving LDS
// instruction count per output. Slots 0..2 are branch-free (p<768<780 always
// active); slot 3 only lives in lanes tid<12.
__global__ __launch_bounds__(256, 4) void ts_corr_r6(const float* __restrict__ in,
                                                     float* __restrict__ out) {
    const int blk = blockIdx.x;
    const int b   = blk / NCHUNK;
    const int c   = blk - b * NCHUNK;
    const int s0  = (c == NCHUNK - 1) ? (NS - SC) : c * SC;   // 439 tail, overlap writes identical-ish
    const int tid = threadIdx.x;

    __shared__ float  xs[SC + WW][FF];   // 74 rows; row 73 is never-used pad (OOB-read shield)
    __shared__ float2 st[SC][FF];        // (u*sqrt(0.1), m*u)

    // ---- phase 0: stage 73-row slab, float4 ----
    const float4* src4 = (const float4*)(in + ((size_t)b * TT + s0) * FF);
    float4* xs4 = (float4*)&xs[0][0];
    #pragma unroll
    for (int k = 0; k < 3; ++k) {
        const int i = tid + k * 256;
        if (i < ROWS * FF / 4) xs4[i] = src4[i];
    }
    __syncthreads();

    // ---- phase 1: stats for all 64 steps, 640 feature-quads ----
    #pragma unroll
    for (int k = 0; k < 3; ++k) {
        const int qd = tid + k * 256;
        if (qd < SC * FF / 4) {
            const int t  = qd / 10;
            const int f0 = (qd - t * 10) * 4;
            float sx0=0,sx1=0,sx2=0,sx3=0, sq0=0,sq1=0,sq2=0,sq3=0;
            #pragma unroll
            for (int w = 0; w < WW; ++w) {
                const float4 x = *(const float4*)&xs[t + w][f0];
                sx0 += x.x; sx1 += x.y; sx2 += x.z; sx3 += x.w;
                sq0 += x.x*x.x; sq1 += x.y*x.y; sq2 += x.z*x.z; sq3 += x.w*x.w;
            }
            const float m0 = sx0*0.1f, m1 = sx1*0.1f, m2 = sx2*0.1f, m3 = sx3*0.1f;
            const float u0 = 1.f/(sqrtf(fmaxf(sq0*0.1f - m0*m0, 0.f)) + EPSC);
            const float u1 = 1.f/(sqrtf(fmaxf(sq1*0.1f - m1*m1, 0.f)) + EPSC);
            const float u2 = 1.f/(sqrtf(fmaxf(sq2*0.1f - m2*m2, 0.f)) + EPSC);
            const float u3 = 1.f/(sqrtf(fmaxf(sq3*0.1f - m3*m3, 0.f)) + EPSC);
            *(float4*)&st[t][f0]     = make_float4(u0*C01, m0*u0, u1*C01, m1*u1);
            *(float4*)&st[t][f0 + 2] = make_float4(u2*C01, m2*u2, u3*C01, m3*u3);
        }
    }

    // ---- pair setup + initial window products (xs ready) ----
    int pi[4], pj[4];
    float sxy[4], ph[4][WW];
    #pragma unroll
    for (int k = 0; k < 4; ++k) {
        const int p = tid + k * 256;
        const int pp = (p < NP) ? p : 0;
        int i = (int)((79.0f - sqrtf((float)(6241 - 8 * pp))) * 0.5f);
        while (i > 0 && i * (79 - i) / 2 > pp) --i;
        while ((i + 1) * (79 - (i + 1)) / 2 <= pp) ++i;
        pi[k] = i;
        pj[k] = pp - i * (79 - i) / 2 + i + 1;
        float s = 0.f;
        #pragma unroll
        for (int w = 0; w < WW; ++w) {
            const float pr = xs[w][pi[k]] * xs[w][pj[k]];
            ph[k][w] = pr;
            s += pr;
        }
        sxy[k] = s;
    }
    __syncthreads();   // st ready; no barriers after this

    float* dst0 = out + (size_t)(b * NS + s0) * NP + tid;

// Two steps (TA, TA+1) per expansion. U is compile-time (static ph index).
// All LDS reads hoisted and paired for ds_read2 merging; DO2 is a literal.
#define STEP2(U, TA, DO2) do {                                                  \
    const int _tA = (TA);                                                       \
    float* _dA = dst0 + (size_t)_tA * NP;                                       \
    float* _dB = _dA + NP;                                                      \
    _Pragma("unroll")                                                           \
    for (int k = 0; k < 3; ++k) {                                               \
        const int _ii = pi[k], _jj = pj[k];                                     \
        const float  _xiA = xs[_tA + WW][_ii], _xiB = xs[_tA + WW + 1][_ii];    \
        const float  _xjA = xs[_tA + WW][_jj], _xjB = xs[_tA + WW + 1][_jj];    \
        const float2 _siA = st[_tA][_ii],      _siB = st[_tA + 1][_ii];         \
        const float2 _sjA = st[_tA][_jj],      _sjB = st[_tA + 1][_jj];         \
        _dA[k * 256] = sxy[k] * _siA.x * _sjA.x - _siA.y * _sjA.y;              \
        const float _pn = _xiA * _xjA;                                          \
        sxy[k] += _pn - ph[k][U]; ph[k][U] = _pn;                               \
        _dB[k * 256] = sxy[k] * _siB.x * _sjB.x - _siB.y * _sjB.y;              \
        if (DO2) {                                                              \
            const float _p2 = _xiB * _xjB;                                      \
            sxy[k] += _p2 - ph[k][(U) + 1]; ph[k][(U) + 1] = _p2;               \
        }                                                                       \
    }                                                                           \
    if (tid < 12) {                                                             \
        const int _ii = pi[3], _jj = pj[3];                                     \
        const float  _xiA = xs[_tA + WW][_ii], _xiB = xs[_tA + WW + 1][_ii];    \
        const float  _xjA = xs[_tA + WW][_jj], _xjB = xs[_tA + WW + 1][_jj];    \
        const float2 _siA = st[_tA][_ii],      _siB = st[_tA + 1][_ii];         \
        const float2 _sjA = st[_tA][_jj],      _sjB = st[_tA + 1][_jj];         \
        _dA[768] = sxy[3] * _siA.x * _sjA.x - _siA.y * _sjA.y;                  \
        const float _pn = _xiA * _xjA;                                          \
        sxy[3] += _pn - ph[3][U]; ph[3][U] = _pn;                               \
        _dB[768] = sxy[3] * _siB.x * _sjB.x - _siB.y * _sjB.y;                  \
        if (DO2) {                                                              \
            const float _p2 = _xiB * _xjB;                                      \
            sxy[3] += _p2 - ph[3][(U) + 1]; ph[3][(U) + 1] = _p2;               \
        }                                                                       \
    }                                                                           \
} while (0)

    // ---- phase 2: t0 = 0..50 fully regular (updates always in-bounds) ----
    for (int t0 = 0; t0 < 60; t0 += WW) {
        STEP2(0, t0,     true);
        STEP2(2, t0 + 2, true);
        STEP2(4, t0 + 4, true);
        STEP2(6, t0 + 6, true);
        STEP2(8, t0 + 8, true);
    }
    // ---- epilogue: t = 60..63; last pair skips the final (OOB) update ----
    STEP2(0, 60, true);
    STEP2(2, 62, false);
#undef STEP2
}

extern "C" void kernel_launch(void* const* d_in, const int* in_sizes, int n_in,
                              void* d_out, int out_size, void* d_ws, size_t ws_size,
                              hipStream_t stream) {
    const float* in = (const float*)d_in[0];
    float* out = (float*)d_out;
    ts_corr_r6<<<BB * NCHUNK, 256, 0, stream>>>(in, out);
}